// Round 6
// baseline (362.461 us; speedup 1.0000x reference)
//
#include <hip/hip_runtime.h>
#include <hip/hip_bf16.h>

#define B_DIM 4
#define C_DIM 192
#define T_SEQ 2048
#define H_DIM 2
#define K_DIM 96
#define BAND 256
#define IT 32            // q rows per attn block (window still <= 544 slots)
#define NJT 34           // j-tiles of 16 in window
#define WSLOT 544        // padded window slots
#define WPD 556          // score row stride in dwords (16B aligned)
#define PRS (2*WPD)      // prob row stride in shorts (bf16 overlay of ps)
#define XSTR 200         // proj LDS row stride in shorts (breaks 16-way conflict)
#define PDS 40           // pd row stride in shorts

typedef __attribute__((ext_vector_type(8))) short bf16x8;
typedef __attribute__((ext_vector_type(4))) short bf16x4;
typedef __attribute__((ext_vector_type(4))) float f32x4;
#define MFMA16 __builtin_amdgcn_mfma_f32_16x16x32_bf16

__device__ __forceinline__ short f2bf_bits(float f) {
    union { __hip_bfloat16 h; short s; } u; u.h = __float2bfloat16(f); return u.s;
}

// ---- workspace layout (bytes) ----
// WqT|WkT|WvT|WoT bf16 [192][192] (WqT prescaled by qscale*log2e); bqs fp32[192];
// relkbf bf16[16][96] (rows 9..15 zero); rvt bf16[96][32] (relv^T, cols 9..31 zero);
// qbf,kbf bf16 [bh][t][96]; vtb bf16 [bh][96][t]; obtc bf16 [b][t][192];
// cnt int[256] (pair-completion counters, zeroed by prep each iteration)
#define OFF_WT(m)  ((size_t)(m)*73728)
#define OFF_BQS    ((size_t)294912)
#define OFF_RELKBF ((size_t)295680)
#define OFF_RVT    ((size_t)298752)
#define OFF_QBF    ((size_t)304896)
#define OFF_KBF    (OFF_QBF + 3145728)
#define OFF_VTB    (OFF_KBF + 3145728)
#define OFF_OBTC   (OFF_VTB + 3145728)
#define OFF_CNT    (OFF_OBTC + 3145728)

// ---------------------------------------------------------------------------
// Prep: [0,144) LDS-tiled weight transpose (coalesced both sides);
// 144: scaled bias + rel-k + relv^T tables + zero pair counters.
// NOTE: qscale includes log2(e) -> scores come out in log2 domain, so the
// softmax uses exp2 (raw v_exp_f32) and a log2(1+d) proximal-bias table.
// ---------------------------------------------------------------------------
__global__ __launch_bounds__(256)
void prep_kernel(const float* __restrict__ Wq, const float* __restrict__ Wk,
                 const float* __restrict__ Wv, const float* __restrict__ Wo,
                 const float* __restrict__ bq, const float* __restrict__ relk,
                 const float* __restrict__ relv, char* __restrict__ ws)
{
    const float qscale = 0.14724445972f;   // (1/sqrt(96)) * log2(e)
    const int bidx = blockIdx.x;
    const int tid  = threadIdx.x;

    if (bidx < 144) {                       // ---- 32x32 tile transpose via LDS
        __shared__ float tile[32][33];
        const int mi = bidx / 36, tl = bidx % 36;
        const int R0 = (tl / 6) * 32, C0 = (tl % 6) * 32;   // R0: c-rows, C0: d-cols
        const float* src = (mi == 0) ? Wq : (mi == 1) ? Wk : (mi == 2) ? Wv : Wo;
        const int r = tid >> 5, cc = tid & 31;
        #pragma unroll
        for (int i = 0; i < 4; ++i) {
            const int rr = r + 8*i;
            tile[rr][cc] = src[(R0 + rr)*C_DIM + C0 + cc];   // coalesced 128B
        }
        __syncthreads();
        short* dst = (short*)(ws + OFF_WT(mi));
        #pragma unroll
        for (int i = 0; i < 4; ++i) {
            const int rr = r + 8*i;                 // d-row within tile
            float v = tile[cc][rr];                 // conflict-free (stride 33)
            if (mi == 0) v *= qscale;
            dst[(C0 + rr)*C_DIM + R0 + cc] = f2bf_bits(v);   // coalesced 64B
        }
        return;
    }
    if (tid < C_DIM)
        ((float*)(ws + OFF_BQS))[tid] = bq[tid]*qscale;
    if (tid >= 192 && tid < 192 + 64) {            // zero 256 counters (int4 x 64)
        int4* cnt4 = (int4*)(ws + OFF_CNT);
        cnt4[tid - 192] = make_int4(0, 0, 0, 0);
    }
    short* rkb = (short*)(ws + OFF_RELKBF);
    for (int idx = tid; idx < 16*K_DIM; idx += 256) {
        const int row = idx / K_DIM;
        rkb[idx] = (row < 9) ? f2bf_bits(relk[idx]) : (short)0;
    }
    short* rvt = (short*)(ws + OFF_RVT);
    for (int idx = tid; idx < K_DIM*32; idx += 256) {
        const int col = idx >> 5, dd = idx & 31;
        rvt[idx] = (dd < 9) ? f2bf_bits(relv[dd*K_DIM + col]) : (short)0;
    }
}

// ---------------------------------------------------------------------------
// Kernel 1: q/k/v projection, one matrix per block, T=32 rows per block
// (weights amortized 2x vs T=16). Grid 768, 256 thr, 4 waves x 3 dt x 2 rt.
// ---------------------------------------------------------------------------
__global__ __launch_bounds__(256)
void proj_kernel(const float* __restrict__ x, const float* __restrict__ cin,
                 const float* __restrict__ bk, const float* __restrict__ bv,
                 char* __restrict__ ws)
{
    __shared__ short sb[2*IT*XSTR/2];   // [32 t][XSTR c] bf16 = 12.8 KB
    const int hw = blockIdx.x;
    const int L  = (hw & 7)*96 + (hw >> 3);    // 768-block XCD-chunked swizzle
    const int which = L % 3;                   // 0=q, 1=k, 2=v
    const int rest  = L / 3;                   // 0..255
    const int b  = rest >> 6;
    const int t0 = (rest & 63) * 32;
    const int tid = threadIdx.x;
    const int wave = tid >> 6, lane = tid & 63;
    const int q4 = lane >> 4, lr = lane & 15;

    const float* src = (which == 0) ? x : cin;
    for (int l = tid; l < 1536; l += 256) {    // 192 c-rows x 8 float4 chunks
        const int cr = l >> 3, u = l & 7;
        const float4 v4 = *reinterpret_cast<const float4*>(
            src + (size_t)(b*C_DIM + cr)*T_SEQ + t0 + 4*u);
        sb[(4*u+0)*XSTR + cr] = f2bf_bits(v4.x);
        sb[(4*u+1)*XSTR + cr] = f2bf_bits(v4.y);
        sb[(4*u+2)*XSTR + cr] = f2bf_bits(v4.z);
        sb[(4*u+3)*XSTR + cr] = f2bf_bits(v4.w);
    }
    __syncthreads();

    const short* WT = (const short*)(ws + OFF_WT(which));
    f32x4 a[3][2];
    #pragma unroll
    for (int j = 0; j < 3; ++j) {
        a[j][0] = (f32x4){0.f,0.f,0.f,0.f};
        a[j][1] = (f32x4){0.f,0.f,0.f,0.f};
    }
    for (int kc = 0; kc < 6; ++kc) {
        const int ko = kc*32 + q4*8;
        const bf16x8 sf0 = *reinterpret_cast<const bf16x8*>(sb + lr*XSTR + ko);
        const bf16x8 sf1 = *reinterpret_cast<const bf16x8*>(sb + (16 + lr)*XSTR + ko);
        #pragma unroll
        for (int j = 0; j < 3; ++j) {
            const bf16x8 wf = *reinterpret_cast<const bf16x8*>(
                WT + ((3*wave + j)*16 + lr)*C_DIM + ko);
            if (which == 2) {                      // v: m=d, n=t
                a[j][0] = MFMA16(wf, sf0, a[j][0], 0, 0, 0);
                a[j][1] = MFMA16(wf, sf1, a[j][1], 0, 0, 0);
            } else {                               // q,k: m=t, n=d
                a[j][0] = MFMA16(sf0, wf, a[j][0], 0, 0, 0);
                a[j][1] = MFMA16(sf1, wf, a[j][1], 0, 0, 0);
            }
        }
    }

    const float* bqs = (const float*)(ws + OFF_BQS);
    #pragma unroll
    for (int j = 0; j < 3; ++j) {
        const int dt = 3*wave + j;
        if (which <= 1) {    // q,k: col=d=dt*16+lr, row=t
            const int d = dt*16 + lr, h = d/K_DIM, kk = d%K_DIM;
            const int bh = b*H_DIM + h;
            const float bias = (which == 0) ? bqs[d] : bk[d];
            short* dst = (short*)(ws + (which == 0 ? OFF_QBF : OFF_KBF));
            #pragma unroll
            for (int rt = 0; rt < 2; ++rt)
                #pragma unroll
                for (int e = 0; e < 4; ++e) {
                    const int t = t0 + rt*16 + q4*4 + e;
                    dst[((size_t)bh*T_SEQ + t)*K_DIM + kk] = f2bf_bits(a[j][rt][e] + bias);
                }
        } else {             // v: col=t, row=d=dt*16+q4*4+e
            short* vtb = (short*)(ws + OFF_VTB);
            #pragma unroll
            for (int rt = 0; rt < 2; ++rt)
                #pragma unroll
                for (int e = 0; e < 4; ++e) {
                    const int d = dt*16 + q4*4 + e, h = d/K_DIM, kk = d%K_DIM;
                    const int bh = b*H_DIM + h;
                    vtb[((size_t)bh*K_DIM + kk)*T_SEQ + t0 + rt*16 + lr] =
                        f2bf_bits(a[j][rt][e] + bv[d]);
                }
        }
    }
}

// ---------------------------------------------------------------------------
// Kernel 2: banded attention, one head, IT=32 rows per block. 1024 threads
// (16 waves), ~72 KB LDS -> 2 blocks/CU = 32 waves/CU (full TLP).
// Mask read directly as int4 in softmax. Base-2 softmax.
// Last-finisher of each (b,i0) head-pair runs the Wo projection tail
// (oproj kernel eliminated). Pair blocks share an XCD by swizzle.
// ---------------------------------------------------------------------------
__global__ __launch_bounds__(1024, 8)
void attn_kernel(const int* __restrict__ mask, const float* __restrict__ bo,
                 float* __restrict__ y, char* __restrict__ ws)
{
    __shared__ __align__(16) float ps[IT*WPD];  // 71168 B scores -> bf16 probs
    __shared__ float lt[257];                   // log2(1+d) table
    __shared__ __align__(16) char upool[2560];  // rl(1152) | pd(2560)
    __shared__ int tailflag;
    float* rl   = (float*)upool;                // [32][9]
    short* pd_s = (short*)upool;                // [32][PDS] (after rl dead)

    const short* qbf = (const short*)(ws + OFF_QBF);
    const short* kbf = (const short*)(ws + OFF_KBF);
    const short* vtb = (const short*)(ws + OFF_VTB);
    const short* rkb = (const short*)(ws + OFF_RELKBF);
    const short* rvt = (const short*)(ws + OFF_RVT);
    short* obtc = (short*)(ws + OFF_OBTC);

    const int L    = ((blockIdx.x & 7) << 6) + (blockIdx.x >> 3);  // 512 blocks
    const int b    = L >> 7;
    const int rem  = L & 127;
    const int i0   = (rem >> 1) * IT;
    const int head = rem & 1;                   // head pairs adjacent -> same XCD
    const int tid  = threadIdx.x;
    const int wave = tid >> 6, lane = tid & 63;
    const int q4 = lane >> 4, lr = lane & 15;
    const int ri = wave & 1, wg = wave >> 1;    // row-tile / job group

    const int jlo  = max(0, i0 - BAND);
    const int jhi  = min(T_SEQ - 1, i0 + IT - 1 + BAND);
    const int wlen = jhi - jlo + 1;             // <= 544
    const size_t qk_base = (size_t)(b*H_DIM + head) * T_SEQ * K_DIM;

    for (int idx = tid; idx < 257; idx += 1024) lt[idx] = log2f((float)(1 + idx));

    // ---- Q A-frags for this wave's row-tile
    bf16x8 qa[3];
    {
        const short* qrow = qbf + qk_base + (size_t)(i0 + ri*16 + lr)*K_DIM + q4*8;
        #pragma unroll
        for (int kc = 0; kc < 3; ++kc)
            qa[kc] = *reinterpret_cast<const bf16x8*>(qrow + kc*32);
    }

    // ---- scores: 68 (jt,ri) jobs over 16 waves
    for (int jt = wg; jt < NJT; jt += 8) {
        int jr = jlo + jt*16 + lr;
        if (jr > T_SEQ-1) jr = T_SEQ-1;
        const short* krow = kbf + qk_base + (size_t)jr*K_DIM + q4*8;
        f32x4 s = {0.f,0.f,0.f,0.f};
        #pragma unroll
        for (int kc = 0; kc < 3; ++kc)
            s = MFMA16(qa[kc], *reinterpret_cast<const bf16x8*>(krow + kc*32), s, 0, 0, 0);
        float* pr = ps + (ri*16 + q4*4)*WPD + jt*16 + lr;
        pr[0*WPD] = s[0]; pr[1*WPD] = s[1]; pr[2*WPD] = s[2]; pr[3*WPD] = s[3];
    }
    if (wg == 7) {                    // rl[r][dd] = q_r . relk_dd (log2 domain)
        const short* krow = rkb + lr*K_DIM + q4*8;
        f32x4 rs = {0.f,0.f,0.f,0.f};
        #pragma unroll
        for (int kc = 0; kc < 3; ++kc)
            rs = MFMA16(qa[kc], *reinterpret_cast<const bf16x8*>(krow + kc*32), rs, 0, 0, 0);
        if (lr < 9) {
            #pragma unroll
            for (int e = 0; e < 4; ++e)
                rl[(ri*16 + q4*4 + e)*9 + lr] = rs[e];
        }
    }
    __syncthreads();   // B1: scores, lt, rl ready

    // ---- postprocess + softmax: row r by 32 lanes (tid>>5), base-2 domain
    {
        const int r = tid >> 5, sj = tid & 31;
        const int i = i0 + r;
        const int* mrow = mask + ((size_t)b*T_SEQ + i)*T_SEQ;
        float* prow = ps + r*WPD;
        float vals[20];
        float m = -INFINITY;
        #pragma unroll
        for (int mm = 0; mm < 5; ++mm) {
            const int j0 = 4*sj + 128*mm;
            float4 pv = make_float4(0.f,0.f,0.f,0.f);
            int4 mv = make_int4(0,0,0,0);
            if (j0 < wlen) {
                pv = *reinterpret_cast<const float4*>(prow + j0);
                mv = *reinterpret_cast<const int4*>(mrow + jlo + j0);  // aligned, in-row
            }
            const float pe[4] = {pv.x, pv.y, pv.z, pv.w};
            const int me[4] = {mv.x, mv.y, mv.z, mv.w};
            #pragma unroll
            for (int e = 0; e < 4; ++e) {
                const int j = j0 + e;
                float val = -INFINITY;
                if (j0 < wlen && j < wlen) {
                    const int dd = jlo + j - i;
                    const int ad = dd < 0 ? -dd : dd;
                    if (ad <= BAND && me[e] != 0) {
                        val = pe[e] - lt[ad];
                        if ((unsigned)(dd + 4) <= 8u) val += rl[r*9 + dd + 4];
                    }
                }
                vals[mm*4 + e] = val;
                m = fmaxf(m, val);
            }
        }
        #pragma unroll
        for (int off = 16; off > 0; off >>= 1) m = fmaxf(m, __shfl_xor(m, off, 64));
        if (m == -INFINITY) m = 0.f;
        float ssum = 0.f;
        #pragma unroll
        for (int u = 0; u < 20; ++u) { vals[u] = exp2f(vals[u] - m); ssum += vals[u]; }
        #pragma unroll
        for (int off = 16; off > 0; off >>= 1) ssum += __shfl_xor(ssum, off, 64);
        const float inv = ssum > 0.f ? 1.f/ssum : 0.f;
        short* pbrow = (short*)prow;
        #pragma unroll
        for (int mm = 0; mm < 5; ++mm) {
            const int j0 = 4*sj + 128*mm;
            if (j0 < WSLOT) {
                bf16x4 w;
                #pragma unroll
                for (int e = 0; e < 4; ++e) w[e] = f2bf_bits(vals[mm*4+e]*inv);
                *reinterpret_cast<bf16x4*>(pbrow + j0) = w;
            }
        }
    }
    __syncthreads();   // B2: bf16 probs ready; rl dead -> pd pool reusable

    // ---- Pd fill (diagonal gather for rel_v MFMA)
    for (int idx = tid; idx < IT*PDS; idx += 1024) {
        const int r = idx / PDS, kk = idx % PDS;
        short v = 0;
        if (kk < 9) {
            const int jg = i0 + r + kk - 4;
            if (jg >= 0 && jg < T_SEQ)
                v = ((const short*)ps)[r*PRS + (jg - jlo)];
        }
        pd_s[idx] = v;
    }

    // ---- PV: 12 output tiles (2 row-tiles x 6 n-tiles) over waves 0..11
    f32x4 o = {0.f,0.f,0.f,0.f};
    const int pri = wave & 1, pnt = wave >> 1;
    if (wave < 12) {
        const short* pbh = (const short*)ps;
        const short* vbase = vtb + qk_base + (size_t)(pnt*16 + lr)*T_SEQ;
        for (int kc = 0; kc < NJT/2; ++kc) {
            const bf16x8 pa = *reinterpret_cast<const bf16x8*>(
                pbh + (pri*16 + lr)*PRS + kc*32 + q4*8);
            int tc = jlo + kc*32 + q4*8;
            if (tc > T_SEQ-8) tc = T_SEQ-8;
            const bf16x8 vb = *reinterpret_cast<const bf16x8*>(vbase + tc);
            o = MFMA16(pa, vb, o, 0, 0, 0);
        }
    }
    __syncthreads();   // B3: pd ready

    if (wave < 12) {
        // rel_v contribution: one MFMA
        const bf16x8 pda = *reinterpret_cast<const bf16x8*>(pd_s + (pri*16 + lr)*PDS + q4*8);
        const bf16x8 rv  = *reinterpret_cast<const bf16x8*>(rvt + (pnt*16 + lr)*32 + q4*8);
        o = MFMA16(pda, rv, o, 0, 0, 0);
        // store obtc slice
        const int col = head*K_DIM + pnt*16 + lr;
        #pragma unroll
        for (int e = 0; e < 4; ++e) {
            const int i = i0 + pri*16 + q4*4 + e;
            obtc[((size_t)b*T_SEQ + i)*C_DIM + col] = f2bf_bits(o[e]);
        }
    }

    // ---- pair rendezvous: second finisher runs the Wo projection tail
    __threadfence();                 // release obtc stores (device scope)
    __syncthreads();
    if (tid == 0) {
        int* cnt = (int*)(ws + OFF_CNT);
        const int old = atomicAdd(cnt + (b*64 + (i0 >> 5)), 1);
        if (old == 1) __threadfence();   // acquire partner's obtc stores
        tailflag = (old == 1);
    }
    __syncthreads();
    if (!tailflag) return;

    // ---- oproj tail: 24 jobs (12 d-tiles x 2 row-tiles) over 16 waves
    const short* WoT = (const short*)(ws + OFF_WT(3));
    #pragma unroll
    for (int u = 0; u < 2; ++u) {
        const int j = wave + 16*u;
        if (u == 1 && j >= 24) break;
        const int dt = j % 12, rt = j / 12;
        f32x4 a = {0.f,0.f,0.f,0.f};
        #pragma unroll
        for (int kc = 0; kc < 6; ++kc) {
            const int ko = kc*32 + q4*8;
            const bf16x8 af = *reinterpret_cast<const bf16x8*>(
                WoT + (size_t)(dt*16 + lr)*C_DIM + ko);
            const bf16x8 bf = *reinterpret_cast<const bf16x8*>(
                obtc + ((size_t)b*T_SEQ + i0 + rt*16 + lr)*C_DIM + ko);
            a = MFMA16(af, bf, a, 0, 0, 0);
        }
        #pragma unroll
        for (int e = 0; e < 4; ++e) {
            const int d = dt*16 + q4*4 + e;
            y[((size_t)b*C_DIM + d)*T_SEQ + i0 + rt*16 + lr] = a[e] + bo[d];
        }
    }
}

// ---------------------------------------------------------------------------
extern "C" void kernel_launch(void* const* d_in, const int* in_sizes, int n_in,
                              void* d_out, int out_size, void* d_ws, size_t ws_size,
                              hipStream_t stream)
{
    const float* x    = (const float*)d_in[0];
    const float* c    = (const float*)d_in[1];
    const float* Wq   = (const float*)d_in[2];
    const float* bq   = (const float*)d_in[3];
    const float* Wk   = (const float*)d_in[4];
    const float* bk   = (const float*)d_in[5];
    const float* Wv   = (const float*)d_in[6];
    const float* bv   = (const float*)d_in[7];
    const float* Wo   = (const float*)d_in[8];
    const float* bo   = (const float*)d_in[9];
    const float* relk = (const float*)d_in[10];
    const float* relv = (const float*)d_in[11];
    const int*   mask = (const int*)d_in[12];
    float*       y    = (float*)d_out;
    char*        ws   = (char*)d_ws;

    hipLaunchKernelGGL(prep_kernel, dim3(145), dim3(256), 0, stream,
                       Wq, Wk, Wv, Wo, bq, relk, relv, ws);
    hipLaunchKernelGGL(proj_kernel, dim3(B_DIM*(T_SEQ/32)*3), dim3(256), 0, stream,
                       x, c, bk, bv, ws);
    hipLaunchKernelGGL(attn_kernel, dim3(B_DIM*H_DIM*(T_SEQ/IT)), dim3(1024), 0, stream,
                       mask, bo, y, ws);
}

// Round 7
// 171.269 us; speedup vs baseline: 2.1163x; 2.1163x over previous
//
#include <hip/hip_runtime.h>
#include <hip/hip_bf16.h>

#define B_DIM 4
#define C_DIM 192
#define T_SEQ 2048
#define H_DIM 2
#define K_DIM 96
#define BAND 256
#define IT 32            // q rows per attn block (window still <= 544 slots)
#define NJT 34           // j-tiles of 16 in window
#define WSLOT 544        // padded window slots
#define WPD 556          // score row stride in dwords (16B aligned)
#define PRS (2*WPD)      // prob row stride in shorts (bf16 overlay of ps)
#define XSTR 200         // proj LDS row stride in shorts (breaks 16-way conflict)
#define PDS 40           // pd row stride in shorts

typedef __attribute__((ext_vector_type(8))) short bf16x8;
typedef __attribute__((ext_vector_type(4))) short bf16x4;
typedef __attribute__((ext_vector_type(4))) float f32x4;
#define MFMA16 __builtin_amdgcn_mfma_f32_16x16x32_bf16

__device__ __forceinline__ short f2bf_bits(float f) {
    union { __hip_bfloat16 h; short s; } u; u.h = __float2bfloat16(f); return u.s;
}

// ---- workspace layout (bytes) ----
// WqT|WkT|WvT|WoT bf16 [192][192] (WqT prescaled by qscale*log2e); bqs fp32[192];
// relkbf bf16[16][96] (rows 9..15 zero); rvt bf16[96][32] (relv^T, cols 9..31 zero);
// qbf,kbf bf16 [bh][t][96]; vtb bf16 [bh][96][t]; obtc bf16 [b][t][192]
#define OFF_WT(m)  ((size_t)(m)*73728)
#define OFF_BQS    ((size_t)294912)
#define OFF_RELKBF ((size_t)295680)
#define OFF_RVT    ((size_t)298752)
#define OFF_QBF    ((size_t)304896)
#define OFF_KBF    (OFF_QBF + 3145728)
#define OFF_VTB    (OFF_KBF + 3145728)
#define OFF_OBTC   (OFF_VTB + 3145728)

// ---------------------------------------------------------------------------
// Prep: [0,144) LDS-tiled weight transpose (coalesced both sides);
// 144: scaled bias + rel-k + relv^T tables.
// NOTE: qscale includes log2(e) -> scores come out in log2 domain, so the
// softmax uses exp2 (raw v_exp_f32) and a log2(1+d) proximal-bias table.
// ---------------------------------------------------------------------------
__global__ __launch_bounds__(256)
void prep_kernel(const float* __restrict__ Wq, const float* __restrict__ Wk,
                 const float* __restrict__ Wv, const float* __restrict__ Wo,
                 const float* __restrict__ bq, const float* __restrict__ relk,
                 const float* __restrict__ relv, char* __restrict__ ws)
{
    const float qscale = 0.14724445972f;   // (1/sqrt(96)) * log2(e)
    const int bidx = blockIdx.x;
    const int tid  = threadIdx.x;

    if (bidx < 144) {                       // ---- 32x32 tile transpose via LDS
        __shared__ float tile[32][33];
        const int mi = bidx / 36, tl = bidx % 36;
        const int R0 = (tl / 6) * 32, C0 = (tl % 6) * 32;   // R0: c-rows, C0: d-cols
        const float* src = (mi == 0) ? Wq : (mi == 1) ? Wk : (mi == 2) ? Wv : Wo;
        const int r = tid >> 5, cc = tid & 31;
        #pragma unroll
        for (int i = 0; i < 4; ++i) {
            const int rr = r + 8*i;
            tile[rr][cc] = src[(R0 + rr)*C_DIM + C0 + cc];   // coalesced 128B
        }
        __syncthreads();
        short* dst = (short*)(ws + OFF_WT(mi));
        #pragma unroll
        for (int i = 0; i < 4; ++i) {
            const int rr = r + 8*i;                 // d-row within tile
            float v = tile[cc][rr];                 // conflict-free (stride 33)
            if (mi == 0) v *= qscale;
            dst[(C0 + rr)*C_DIM + R0 + cc] = f2bf_bits(v);   // coalesced 64B
        }
        return;
    }
    if (tid < C_DIM)
        ((float*)(ws + OFF_BQS))[tid] = bq[tid]*qscale;
    short* rkb = (short*)(ws + OFF_RELKBF);
    for (int idx = tid; idx < 16*K_DIM; idx += 256) {
        const int row = idx / K_DIM;
        rkb[idx] = (row < 9) ? f2bf_bits(relk[idx]) : (short)0;
    }
    short* rvt = (short*)(ws + OFF_RVT);
    for (int idx = tid; idx < K_DIM*32; idx += 256) {
        const int col = idx >> 5, dd = idx & 31;
        rvt[idx] = (dd < 9) ? f2bf_bits(relv[dd*K_DIM + col]) : (short)0;
    }
}

// ---------------------------------------------------------------------------
// Kernel 1: projection. Block type 0 computes q from x; type 1 computes BOTH
// k and v from one staged c tile (c read once, not twice). Grid 512, 256 thr.
// Swizzle keeps (q,kv) of a tile and the downstream attn head pair on one XCD.
// ---------------------------------------------------------------------------
__global__ __launch_bounds__(256)
void proj_kernel(const float* __restrict__ x, const float* __restrict__ cin,
                 const float* __restrict__ bk, const float* __restrict__ bv,
                 char* __restrict__ ws)
{
    __shared__ short sb[IT*XSTR];   // [32 t][XSTR c] bf16 = 12.8 KB
    const int hw = blockIdx.x;
    const int L  = ((hw & 7) << 6) + (hw >> 3);   // 512-block XCD-chunked swizzle
    const int which = L & 1;                      // 0=q (from x), 1=kv (from c)
    const int rest  = L >> 1;                     // 0..255
    const int b  = rest >> 6;
    const int t0 = (rest & 63) * 32;
    const int tid = threadIdx.x;
    const int wave = tid >> 6, lane = tid & 63;
    const int q4 = lane >> 4, lr = lane & 15;

    const float* src = (which == 0) ? x : cin;
    for (int l = tid; l < 1536; l += 256) {    // 192 c-rows x 8 float4 chunks
        const int cr = l >> 3, u = l & 7;
        const float4 v4 = *reinterpret_cast<const float4*>(
            src + (size_t)(b*C_DIM + cr)*T_SEQ + t0 + 4*u);
        sb[(4*u+0)*XSTR + cr] = f2bf_bits(v4.x);
        sb[(4*u+1)*XSTR + cr] = f2bf_bits(v4.y);
        sb[(4*u+2)*XSTR + cr] = f2bf_bits(v4.z);
        sb[(4*u+3)*XSTR + cr] = f2bf_bits(v4.w);
    }
    __syncthreads();

    if (which == 0) {       // ---- q projection (m=t, n=d), prescaled WqT
        const short* WT = (const short*)(ws + OFF_WT(0));
        f32x4 a[3][2];
        #pragma unroll
        for (int j = 0; j < 3; ++j) {
            a[j][0] = (f32x4){0.f,0.f,0.f,0.f};
            a[j][1] = (f32x4){0.f,0.f,0.f,0.f};
        }
        for (int kc = 0; kc < 6; ++kc) {
            const int ko = kc*32 + q4*8;
            const bf16x8 sf0 = *reinterpret_cast<const bf16x8*>(sb + lr*XSTR + ko);
            const bf16x8 sf1 = *reinterpret_cast<const bf16x8*>(sb + (16 + lr)*XSTR + ko);
            #pragma unroll
            for (int j = 0; j < 3; ++j) {
                const bf16x8 wf = *reinterpret_cast<const bf16x8*>(
                    WT + ((3*wave + j)*16 + lr)*C_DIM + ko);
                a[j][0] = MFMA16(sf0, wf, a[j][0], 0, 0, 0);
                a[j][1] = MFMA16(sf1, wf, a[j][1], 0, 0, 0);
            }
        }
        const float* bqs = (const float*)(ws + OFF_BQS);
        short* qbf = (short*)(ws + OFF_QBF);
        #pragma unroll
        for (int j = 0; j < 3; ++j) {
            const int d = (3*wave + j)*16 + lr, h = d/K_DIM, kk = d%K_DIM;
            const int bh = b*H_DIM + h;
            const float bias = bqs[d];
            #pragma unroll
            for (int rt = 0; rt < 2; ++rt)
                #pragma unroll
                for (int e = 0; e < 4; ++e) {
                    const int t = t0 + rt*16 + q4*4 + e;
                    qbf[((size_t)bh*T_SEQ + t)*K_DIM + kk] = f2bf_bits(a[j][rt][e] + bias);
                }
        }
    } else {                // ---- k (m=t,n=d) AND v (m=d,n=t) from one c tile
        const short* WkT = (const short*)(ws + OFF_WT(1));
        const short* WvT = (const short*)(ws + OFF_WT(2));
        f32x4 ka[3][2], va[3][2];
        #pragma unroll
        for (int j = 0; j < 3; ++j) {
            ka[j][0] = (f32x4){0.f,0.f,0.f,0.f}; ka[j][1] = (f32x4){0.f,0.f,0.f,0.f};
            va[j][0] = (f32x4){0.f,0.f,0.f,0.f}; va[j][1] = (f32x4){0.f,0.f,0.f,0.f};
        }
        for (int kc = 0; kc < 6; ++kc) {
            const int ko = kc*32 + q4*8;
            const bf16x8 sf0 = *reinterpret_cast<const bf16x8*>(sb + lr*XSTR + ko);
            const bf16x8 sf1 = *reinterpret_cast<const bf16x8*>(sb + (16 + lr)*XSTR + ko);
            #pragma unroll
            for (int j = 0; j < 3; ++j) {
                const bf16x8 wkf = *reinterpret_cast<const bf16x8*>(
                    WkT + ((3*wave + j)*16 + lr)*C_DIM + ko);
                const bf16x8 wvf = *reinterpret_cast<const bf16x8*>(
                    WvT + ((3*wave + j)*16 + lr)*C_DIM + ko);
                ka[j][0] = MFMA16(sf0, wkf, ka[j][0], 0, 0, 0);
                ka[j][1] = MFMA16(sf1, wkf, ka[j][1], 0, 0, 0);
                va[j][0] = MFMA16(wvf, sf0, va[j][0], 0, 0, 0);
                va[j][1] = MFMA16(wvf, sf1, va[j][1], 0, 0, 0);
            }
        }
        short* kbf = (short*)(ws + OFF_KBF);
        short* vtb = (short*)(ws + OFF_VTB);
        #pragma unroll
        for (int j = 0; j < 3; ++j) {
            {   // k: col=d, row=t
                const int d = (3*wave + j)*16 + lr, h = d/K_DIM, kk = d%K_DIM;
                const int bh = b*H_DIM + h;
                const float bias = bk[d];
                #pragma unroll
                for (int rt = 0; rt < 2; ++rt)
                    #pragma unroll
                    for (int e = 0; e < 4; ++e) {
                        const int t = t0 + rt*16 + q4*4 + e;
                        kbf[((size_t)bh*T_SEQ + t)*K_DIM + kk] = f2bf_bits(ka[j][rt][e] + bias);
                    }
            }
            {   // v: col=t, row=d
                #pragma unroll
                for (int rt = 0; rt < 2; ++rt)
                    #pragma unroll
                    for (int e = 0; e < 4; ++e) {
                        const int d = (3*wave + j)*16 + q4*4 + e, h = d/K_DIM, kk = d%K_DIM;
                        const int bh = b*H_DIM + h;
                        vtb[((size_t)bh*K_DIM + kk)*T_SEQ + t0 + rt*16 + lr] =
                            f2bf_bits(va[j][rt][e] + bv[d]);
                    }
            }
        }
    }
}

// ---------------------------------------------------------------------------
// Kernel 2: banded attention, one head, IT=32 rows per block. 1024 threads
// (16 waves), ~72 KB LDS -> 2 blocks/CU = 32 waves/CU (full TLP).
// Mask read directly as int4 in softmax. Base-2 softmax. (Round-5 verbatim.)
// ---------------------------------------------------------------------------
__global__ __launch_bounds__(1024, 8)
void attn_kernel(const int* __restrict__ mask, char* __restrict__ ws)
{
    __shared__ __align__(16) float ps[IT*WPD];  // 71168 B scores -> bf16 probs
    __shared__ float lt[257];                   // log2(1+d) table
    __shared__ __align__(16) char upool[2560];  // rl(1152) | pd(2560)
    float* rl   = (float*)upool;                // [32][9]
    short* pd_s = (short*)upool;                // [32][PDS] (after rl dead)

    const short* qbf = (const short*)(ws + OFF_QBF);
    const short* kbf = (const short*)(ws + OFF_KBF);
    const short* vtb = (const short*)(ws + OFF_VTB);
    const short* rkb = (const short*)(ws + OFF_RELKBF);
    const short* rvt = (const short*)(ws + OFF_RVT);
    short* obtc = (short*)(ws + OFF_OBTC);

    const int L    = ((blockIdx.x & 7) << 6) + (blockIdx.x >> 3);  // 512 blocks
    const int b    = L >> 7;
    const int rem  = L & 127;
    const int i0   = (rem >> 1) * IT;
    const int head = rem & 1;                   // head pairs share an XCD
    const int tid  = threadIdx.x;
    const int wave = tid >> 6, lane = tid & 63;
    const int q4 = lane >> 4, lr = lane & 15;
    const int ri = wave & 1, wg = wave >> 1;    // row-tile / job group

    const int jlo  = max(0, i0 - BAND);
    const int jhi  = min(T_SEQ - 1, i0 + IT - 1 + BAND);
    const int wlen = jhi - jlo + 1;             // <= 544
    const size_t qk_base = (size_t)(b*H_DIM + head) * T_SEQ * K_DIM;

    for (int idx = tid; idx < 257; idx += 1024) lt[idx] = log2f((float)(1 + idx));

    // ---- Q A-frags for this wave's row-tile
    bf16x8 qa[3];
    {
        const short* qrow = qbf + qk_base + (size_t)(i0 + ri*16 + lr)*K_DIM + q4*8;
        #pragma unroll
        for (int kc = 0; kc < 3; ++kc)
            qa[kc] = *reinterpret_cast<const bf16x8*>(qrow + kc*32);
    }

    // ---- scores: 68 (jt,ri) jobs over 16 waves
    for (int jt = wg; jt < NJT; jt += 8) {
        int jr = jlo + jt*16 + lr;
        if (jr > T_SEQ-1) jr = T_SEQ-1;
        const short* krow = kbf + qk_base + (size_t)jr*K_DIM + q4*8;
        f32x4 s = {0.f,0.f,0.f,0.f};
        #pragma unroll
        for (int kc = 0; kc < 3; ++kc)
            s = MFMA16(qa[kc], *reinterpret_cast<const bf16x8*>(krow + kc*32), s, 0, 0, 0);
        float* pr = ps + (ri*16 + q4*4)*WPD + jt*16 + lr;
        pr[0*WPD] = s[0]; pr[1*WPD] = s[1]; pr[2*WPD] = s[2]; pr[3*WPD] = s[3];
    }
    if (wg == 7) {                    // rl[r][dd] = q_r . relk_dd (log2 domain)
        const short* krow = rkb + lr*K_DIM + q4*8;
        f32x4 rs = {0.f,0.f,0.f,0.f};
        #pragma unroll
        for (int kc = 0; kc < 3; ++kc)
            rs = MFMA16(qa[kc], *reinterpret_cast<const bf16x8*>(krow + kc*32), rs, 0, 0, 0);
        if (lr < 9) {
            #pragma unroll
            for (int e = 0; e < 4; ++e)
                rl[(ri*16 + q4*4 + e)*9 + lr] = rs[e];
        }
    }
    __syncthreads();   // B1: scores, lt, rl ready

    // ---- postprocess + softmax: row r by 32 lanes (tid>>5), base-2 domain
    {
        const int r = tid >> 5, sj = tid & 31;
        const int i = i0 + r;
        const int* mrow = mask + ((size_t)b*T_SEQ + i)*T_SEQ;
        float* prow = ps + r*WPD;
        float vals[20];
        float m = -INFINITY;
        #pragma unroll
        for (int mm = 0; mm < 5; ++mm) {
            const int j0 = 4*sj + 128*mm;
            float4 pv = make_float4(0.f,0.f,0.f,0.f);
            int4 mv = make_int4(0,0,0,0);
            if (j0 < wlen) {
                pv = *reinterpret_cast<const float4*>(prow + j0);
                mv = *reinterpret_cast<const int4*>(mrow + jlo + j0);  // aligned, in-row
            }
            const float pe[4] = {pv.x, pv.y, pv.z, pv.w};
            const int me[4] = {mv.x, mv.y, mv.z, mv.w};
            #pragma unroll
            for (int e = 0; e < 4; ++e) {
                const int j = j0 + e;
                float val = -INFINITY;
                if (j0 < wlen && j < wlen) {
                    const int dd = jlo + j - i;
                    const int ad = dd < 0 ? -dd : dd;
                    if (ad <= BAND && me[e] != 0) {
                        val = pe[e] - lt[ad];
                        if ((unsigned)(dd + 4) <= 8u) val += rl[r*9 + dd + 4];
                    }
                }
                vals[mm*4 + e] = val;
                m = fmaxf(m, val);
            }
        }
        #pragma unroll
        for (int off = 16; off > 0; off >>= 1) m = fmaxf(m, __shfl_xor(m, off, 64));
        if (m == -INFINITY) m = 0.f;
        float ssum = 0.f;
        #pragma unroll
        for (int u = 0; u < 20; ++u) { vals[u] = exp2f(vals[u] - m); ssum += vals[u]; }
        #pragma unroll
        for (int off = 16; off > 0; off >>= 1) ssum += __shfl_xor(ssum, off, 64);
        const float inv = ssum > 0.f ? 1.f/ssum : 0.f;
        short* pbrow = (short*)prow;
        #pragma unroll
        for (int mm = 0; mm < 5; ++mm) {
            const int j0 = 4*sj + 128*mm;
            if (j0 < WSLOT) {
                bf16x4 w;
                #pragma unroll
                for (int e = 0; e < 4; ++e) w[e] = f2bf_bits(vals[mm*4+e]*inv);
                *reinterpret_cast<bf16x4*>(pbrow + j0) = w;
            }
        }
    }
    __syncthreads();   // B2: bf16 probs ready; rl dead -> pd pool reusable

    // ---- Pd fill (diagonal gather for rel_v MFMA)
    for (int idx = tid; idx < IT*PDS; idx += 1024) {
        const int r = idx / PDS, kk = idx % PDS;
        short v = 0;
        if (kk < 9) {
            const int jg = i0 + r + kk - 4;
            if (jg >= 0 && jg < T_SEQ)
                v = ((const short*)ps)[r*PRS + (jg - jlo)];
        }
        pd_s[idx] = v;
    }

    // ---- PV: 12 output tiles (2 row-tiles x 6 n-tiles) over waves 0..11
    f32x4 o = {0.f,0.f,0.f,0.f};
    const int pri = wave & 1, pnt = wave >> 1;
    if (wave < 12) {
        const short* pbh = (const short*)ps;
        const short* vbase = vtb + qk_base + (size_t)(pnt*16 + lr)*T_SEQ;
        for (int kc = 0; kc < NJT/2; ++kc) {
            const bf16x8 pa = *reinterpret_cast<const bf16x8*>(
                pbh + (pri*16 + lr)*PRS + kc*32 + q4*8);
            int tc = jlo + kc*32 + q4*8;
            if (tc > T_SEQ-8) tc = T_SEQ-8;
            const bf16x8 vb = *reinterpret_cast<const bf16x8*>(vbase + tc);
            o = MFMA16(pa, vb, o, 0, 0, 0);
        }
    }
    __syncthreads();   // B3: pd ready

    if (wave < 12) {
        // rel_v contribution: one MFMA
        const bf16x8 pda = *reinterpret_cast<const bf16x8*>(pd_s + (pri*16 + lr)*PDS + q4*8);
        const bf16x8 rv  = *reinterpret_cast<const bf16x8*>(rvt + (pnt*16 + lr)*32 + q4*8);
        o = MFMA16(pda, rv, o, 0, 0, 0);
        // store obtc slice
        const int col = head*K_DIM + pnt*16 + lr;
        #pragma unroll
        for (int e = 0; e < 4; ++e) {
            const int i = i0 + pri*16 + q4*4 + e;
            obtc[((size_t)b*T_SEQ + i)*C_DIM + col] = f2bf_bits(o[e]);
        }
    }
}

// ---------------------------------------------------------------------------
// Kernel 3: output projection, 16-row blocks (grid 512, 2 blocks/CU TLP).
// y^T store (m=d, n=t).
// ---------------------------------------------------------------------------
__global__ __launch_bounds__(256)
void oproj_kernel(const float* __restrict__ bo, float* __restrict__ y,
                  const char* __restrict__ ws)
{
    const int bid = ((blockIdx.x & 7) << 6) + (blockIdx.x >> 3);   // 512 blocks
    const int b   = bid >> 7;
    const int t0  = (bid & 127) * 16;
    const int tid = threadIdx.x;
    const int wave = tid >> 6, lane = tid & 63;
    const int q4 = lane >> 4, lr = lane & 15;

    const short* WoT  = (const short*)(ws + OFF_WT(3));
    const short* obtc = (const short*)(ws + OFF_OBTC);

    f32x4 a[3];
    #pragma unroll
    for (int j = 0; j < 3; ++j) a[j] = (f32x4){0.f,0.f,0.f,0.f};
    for (int kc = 0; kc < 6; ++kc) {
        const int ko = kc*32 + q4*8;
        const bf16x8 bf = *reinterpret_cast<const bf16x8*>(
            obtc + ((size_t)b*T_SEQ + t0 + lr)*C_DIM + ko);
        #pragma unroll
        for (int j = 0; j < 3; ++j) {
            const bf16x8 af = *reinterpret_cast<const bf16x8*>(
                WoT + ((3*wave + j)*16 + lr)*C_DIM + ko);
            a[j] = MFMA16(af, bf, a[j], 0, 0, 0);
        }
    }
    #pragma unroll
    for (int j = 0; j < 3; ++j) {
        #pragma unroll
        for (int e = 0; e < 4; ++e) {
            const int d = (3*wave + j)*16 + q4*4 + e;
            y[((size_t)b*C_DIM + d)*T_SEQ + t0 + lr] = a[j][e] + bo[d];
        }
    }
}

// ---------------------------------------------------------------------------
extern "C" void kernel_launch(void* const* d_in, const int* in_sizes, int n_in,
                              void* d_out, int out_size, void* d_ws, size_t ws_size,
                              hipStream_t stream)
{
    const float* x    = (const float*)d_in[0];
    const float* c    = (const float*)d_in[1];
    const float* Wq   = (const float*)d_in[2];
    const float* bq   = (const float*)d_in[3];
    const float* Wk   = (const float*)d_in[4];
    const float* bk   = (const float*)d_in[5];
    const float* Wv   = (const float*)d_in[6];
    const float* bv   = (const float*)d_in[7];
    const float* Wo   = (const float*)d_in[8];
    const float* bo   = (const float*)d_in[9];
    const float* relk = (const float*)d_in[10];
    const float* relv = (const float*)d_in[11];
    const int*   mask = (const int*)d_in[12];
    float*       y    = (float*)d_out;
    char*        ws   = (char*)d_ws;

    hipLaunchKernelGGL(prep_kernel, dim3(145), dim3(256), 0, stream,
                       Wq, Wk, Wv, Wo, bq, relk, relv, ws);
    hipLaunchKernelGGL(proj_kernel, dim3(B_DIM*(T_SEQ/32)*2), dim3(256), 0, stream,
                       x, c, bk, bv, ws);
    hipLaunchKernelGGL(attn_kernel, dim3(B_DIM*H_DIM*(T_SEQ/IT)), dim3(1024), 0, stream,
                       mask, ws);
    hipLaunchKernelGGL(oproj_kernel, dim3(B_DIM*(T_SEQ/16)), dim3(256), 0, stream,
                       bo, y, ws);
}

// Round 9
// 168.401 us; speedup vs baseline: 2.1524x; 1.0170x over previous
//
#include <hip/hip_runtime.h>
#include <hip/hip_bf16.h>

#define B_DIM 4
#define C_DIM 192
#define T_SEQ 2048
#define H_DIM 2
#define K_DIM 96
#define BAND 256
#define IT 32            // q rows per attn block (window still <= 544 slots)
#define NJT 34           // j-tiles of 16 in window
#define WSLOT 544        // padded window slots
#define WPD 556          // score row stride in dwords (16B aligned)
#define PRS (2*WPD)      // prob row stride in shorts (bf16 overlay of ps)
#define XSTR 200         // proj LDS row stride in shorts (breaks 16-way conflict)
#define PDS 40           // pd row stride in shorts
#define OSTRT 104        // out_s row stride in shorts (208B, 16B-aligned)

typedef __attribute__((ext_vector_type(8))) short bf16x8;
typedef __attribute__((ext_vector_type(4))) short bf16x4;
typedef __attribute__((ext_vector_type(4))) float f32x4;
#define MFMA16 __builtin_amdgcn_mfma_f32_16x16x32_bf16

__device__ __forceinline__ short f2bf_bits(float f) {
    union { __hip_bfloat16 h; short s; } u; u.h = __float2bfloat16(f); return u.s;
}

// ---- workspace layout (bytes) ----
// WqT|WkT|WvT|WoT bf16 [192][192] (WqT prescaled by qscale*log2e); bqs fp32[192];
// relkbf bf16[16][96] (rows 9..15 zero); rvt bf16[96][32] (relv^T, cols 9..31 zero);
// qbf,kbf bf16 [bh][t][96]; vtb bf16 [bh][96][t]
#define OFF_WT(m)  ((size_t)(m)*73728)
#define OFF_BQS    ((size_t)294912)
#define OFF_RELKBF ((size_t)295680)
#define OFF_RVT    ((size_t)298752)
#define OFF_QBF    ((size_t)304896)
#define OFF_KBF    (OFF_QBF + 3145728)
#define OFF_VTB    (OFF_KBF + 3145728)

// ---------------------------------------------------------------------------
// Prep: [0,144) LDS-tiled weight transpose; 144: tables; [145,529): y init
// to bo[d] (attn atomic-adds partial Wo products on top).
// NOTE: qscale includes log2(e) -> scores in log2 domain; softmax uses exp2.
// ---------------------------------------------------------------------------
__global__ __launch_bounds__(256)
void prep_kernel(const float* __restrict__ Wq, const float* __restrict__ Wk,
                 const float* __restrict__ Wv, const float* __restrict__ Wo,
                 const float* __restrict__ bq, const float* __restrict__ relk,
                 const float* __restrict__ relv, const float* __restrict__ bo,
                 float* __restrict__ y, char* __restrict__ ws)
{
    const float qscale = 0.14724445972f;   // (1/sqrt(96)) * log2(e)
    const int bidx = blockIdx.x;
    const int tid  = threadIdx.x;

    if (bidx < 144) {                       // ---- 32x32 tile transpose via LDS
        __shared__ float tile[32][33];
        const int mi = bidx / 36, tl = bidx % 36;
        const int R0 = (tl / 6) * 32, C0 = (tl % 6) * 32;   // R0: c-rows, C0: d-cols
        const float* src = (mi == 0) ? Wq : (mi == 1) ? Wk : (mi == 2) ? Wv : Wo;
        const int r = tid >> 5, cc = tid & 31;
        #pragma unroll
        for (int i = 0; i < 4; ++i) {
            const int rr = r + 8*i;
            tile[rr][cc] = src[(R0 + rr)*C_DIM + C0 + cc];   // coalesced 128B
        }
        __syncthreads();
        short* dst = (short*)(ws + OFF_WT(mi));
        #pragma unroll
        for (int i = 0; i < 4; ++i) {
            const int rr = r + 8*i;                 // d-row within tile
            float v = tile[cc][rr];                 // conflict-free (stride 33)
            if (mi == 0) v *= qscale;
            dst[(C0 + rr)*C_DIM + R0 + cc] = f2bf_bits(v);   // coalesced 64B
        }
        return;
    }
    if (bidx == 144) {                      // ---- tables
        if (tid < C_DIM)
            ((float*)(ws + OFF_BQS))[tid] = bq[tid]*qscale;
        short* rkb = (short*)(ws + OFF_RELKBF);
        for (int idx = tid; idx < 16*K_DIM; idx += 256) {
            const int row = idx / K_DIM;
            rkb[idx] = (row < 9) ? f2bf_bits(relk[idx]) : (short)0;
        }
        short* rvt = (short*)(ws + OFF_RVT);
        for (int idx = tid; idx < K_DIM*32; idx += 256) {
            const int col = idx >> 5, dd = idx & 31;
            rvt[idx] = (dd < 9) ? f2bf_bits(relv[dd*K_DIM + col]) : (short)0;
        }
        return;
    }
    // ---- y init: y[b][d][t] = bo[d]; 16 floats per thread (same d per 16)
    const int gi = (bidx - 145)*256 + tid;          // 384 blocks x 256 thr
    const int base = gi * 16;                       // < 4*192*2048 = 1572864
    const int d = (base >> 11) % C_DIM;             // 2048 t per row, 16 | 2048
    const float v = bo[d];
    float4 v4 = make_float4(v, v, v, v);
    float4* yp = (float4*)(y + base);
    yp[0] = v4; yp[1] = v4; yp[2] = v4; yp[3] = v4;
}

// ---------------------------------------------------------------------------
// Kernel 1: q/k/v projection, one matrix per block, T=32 rows per block
// (round-5 structure). Grid 768, 256 thr, 4 waves x 3 dt x 2 rt.
// ---------------------------------------------------------------------------
__global__ __launch_bounds__(256)
void proj_kernel(const float* __restrict__ x, const float* __restrict__ cin,
                 const float* __restrict__ bk, const float* __restrict__ bv,
                 char* __restrict__ ws)
{
    __shared__ short sb[IT*XSTR];   // [32 t][XSTR c] bf16 = 12.8 KB
    const int hw = blockIdx.x;
    const int L  = (hw & 7)*96 + (hw >> 3);    // 768-block XCD-chunked swizzle
    const int which = L % 3;                   // 0=q, 1=k, 2=v
    const int rest  = L / 3;                   // 0..255
    const int b  = rest >> 6;
    const int t0 = (rest & 63) * 32;
    const int tid = threadIdx.x;
    const int wave = tid >> 6, lane = tid & 63;
    const int q4 = lane >> 4, lr = lane & 15;

    const float* src = (which == 0) ? x : cin;
    for (int l = tid; l < 1536; l += 256) {    // 192 c-rows x 8 float4 chunks
        const int cr = l >> 3, u = l & 7;
        const float4 v4 = *reinterpret_cast<const float4*>(
            src + (size_t)(b*C_DIM + cr)*T_SEQ + t0 + 4*u);
        sb[(4*u+0)*XSTR + cr] = f2bf_bits(v4.x);
        sb[(4*u+1)*XSTR + cr] = f2bf_bits(v4.y);
        sb[(4*u+2)*XSTR + cr] = f2bf_bits(v4.z);
        sb[(4*u+3)*XSTR + cr] = f2bf_bits(v4.w);
    }
    __syncthreads();

    const short* WT = (const short*)(ws + OFF_WT(which));
    f32x4 a[3][2];
    #pragma unroll
    for (int j = 0; j < 3; ++j) {
        a[j][0] = (f32x4){0.f,0.f,0.f,0.f};
        a[j][1] = (f32x4){0.f,0.f,0.f,0.f};
    }
    for (int kc = 0; kc < 6; ++kc) {
        const int ko = kc*32 + q4*8;
        const bf16x8 sf0 = *reinterpret_cast<const bf16x8*>(sb + lr*XSTR + ko);
        const bf16x8 sf1 = *reinterpret_cast<const bf16x8*>(sb + (16 + lr)*XSTR + ko);
        #pragma unroll
        for (int j = 0; j < 3; ++j) {
            const bf16x8 wf = *reinterpret_cast<const bf16x8*>(
                WT + ((3*wave + j)*16 + lr)*C_DIM + ko);
            if (which == 2) {                      // v: m=d, n=t
                a[j][0] = MFMA16(wf, sf0, a[j][0], 0, 0, 0);
                a[j][1] = MFMA16(wf, sf1, a[j][1], 0, 0, 0);
            } else {                               // q,k: m=t, n=d
                a[j][0] = MFMA16(sf0, wf, a[j][0], 0, 0, 0);
                a[j][1] = MFMA16(sf1, wf, a[j][1], 0, 0, 0);
            }
        }
    }

    const float* bqs = (const float*)(ws + OFF_BQS);
    #pragma unroll
    for (int j = 0; j < 3; ++j) {
        const int dt = 3*wave + j;
        if (which <= 1) {    // q,k: col=d=dt*16+lr, row=t
            const int d = dt*16 + lr, h = d/K_DIM, kk = d%K_DIM;
            const int bh = b*H_DIM + h;
            const float bias = (which == 0) ? bqs[d] : bk[d];
            short* dst = (short*)(ws + (which == 0 ? OFF_QBF : OFF_KBF));
            #pragma unroll
            for (int rt = 0; rt < 2; ++rt)
                #pragma unroll
                for (int e = 0; e < 4; ++e) {
                    const int t = t0 + rt*16 + q4*4 + e;
                    dst[((size_t)bh*T_SEQ + t)*K_DIM + kk] = f2bf_bits(a[j][rt][e] + bias);
                }
        } else {             // v: col=t, row=d=dt*16+q4*4+e
            short* vtb = (short*)(ws + OFF_VTB);
            #pragma unroll
            for (int rt = 0; rt < 2; ++rt)
                #pragma unroll
                for (int e = 0; e < 4; ++e) {
                    const int d = dt*16 + q4*4 + e, h = d/K_DIM, kk = d%K_DIM;
                    const int bh = b*H_DIM + h;
                    vtb[((size_t)bh*K_DIM + kk)*T_SEQ + t0 + rt*16 + lr] =
                        f2bf_bits(a[j][rt][e] + bv[d]);
                }
        }
    }
}

// ---------------------------------------------------------------------------
// Kernel 2: banded attention, one head, IT=32 rows per block. 1024 threads
// (16 waves), ~72 KB LDS -> 2 blocks/CU = 32 waves/CU (full TLP).
// Round-5 body + fused per-head output-projection tail: each block computes
// its head's 192x32 partial Wo product from LDS and atomicAdds into y
// (y pre-initialized to bo by prep). No cross-block sync, no fences.
// ---------------------------------------------------------------------------
__global__ __launch_bounds__(1024, 8)
void attn_kernel(const int* __restrict__ mask, float* __restrict__ y,
                 char* __restrict__ ws)
{
    __shared__ __align__(16) float ps[IT*WPD];  // 71168 B scores -> probs -> out_s
    __shared__ float lt[257];                   // log2(1+d) table
    __shared__ __align__(16) char upool[2560];  // rl(1152) | pd(2560)
    float* rl   = (float*)upool;                // [32][9]
    short* pd_s = (short*)upool;                // [32][PDS] (after rl dead)

    const short* qbf = (const short*)(ws + OFF_QBF);
    const short* kbf = (const short*)(ws + OFF_KBF);
    const short* vtb = (const short*)(ws + OFF_VTB);
    const short* rkb = (const short*)(ws + OFF_RELKBF);
    const short* rvt = (const short*)(ws + OFF_RVT);

    const int L    = ((blockIdx.x & 7) << 6) + (blockIdx.x >> 3);  // 512 blocks
    const int b    = L >> 7;
    const int rem  = L & 127;
    const int i0   = (rem >> 1) * IT;
    const int head = rem & 1;                   // head pairs share an XCD
    const int tid  = threadIdx.x;
    const int wave = tid >> 6, lane = tid & 63;
    const int q4 = lane >> 4, lr = lane & 15;
    const int ri = wave & 1, wg = wave >> 1;    // row-tile / job group

    const int jlo  = max(0, i0 - BAND);
    const int jhi  = min(T_SEQ - 1, i0 + IT - 1 + BAND);
    const int wlen = jhi - jlo + 1;             // <= 544
    const size_t qk_base = (size_t)(b*H_DIM + head) * T_SEQ * K_DIM;

    for (int idx = tid; idx < 257; idx += 1024) lt[idx] = log2f((float)(1 + idx));

    // ---- Q A-frags for this wave's row-tile
    bf16x8 qa[3];
    {
        const short* qrow = qbf + qk_base + (size_t)(i0 + ri*16 + lr)*K_DIM + q4*8;
        #pragma unroll
        for (int kc = 0; kc < 3; ++kc)
            qa[kc] = *reinterpret_cast<const bf16x8*>(qrow + kc*32);
    }

    // ---- scores: 68 (jt,ri) jobs over 16 waves
    for (int jt = wg; jt < NJT; jt += 8) {
        int jr = jlo + jt*16 + lr;
        if (jr > T_SEQ-1) jr = T_SEQ-1;
        const short* krow = kbf + qk_base + (size_t)jr*K_DIM + q4*8;
        f32x4 s = {0.f,0.f,0.f,0.f};
        #pragma unroll
        for (int kc = 0; kc < 3; ++kc)
            s = MFMA16(qa[kc], *reinterpret_cast<const bf16x8*>(krow + kc*32), s, 0, 0, 0);
        float* pr = ps + (ri*16 + q4*4)*WPD + jt*16 + lr;
        pr[0*WPD] = s[0]; pr[1*WPD] = s[1]; pr[2*WPD] = s[2]; pr[3*WPD] = s[3];
    }
    if (wg == 7) {                    // rl[r][dd] = q_r . relk_dd (log2 domain)
        const short* krow = rkb + lr*K_DIM + q4*8;
        f32x4 rs = {0.f,0.f,0.f,0.f};
        #pragma unroll
        for (int kc = 0; kc < 3; ++kc)
            rs = MFMA16(qa[kc], *reinterpret_cast<const bf16x8*>(krow + kc*32), rs, 0, 0, 0);
        if (lr < 9) {
            #pragma unroll
            for (int e = 0; e < 4; ++e)
                rl[(ri*16 + q4*4 + e)*9 + lr] = rs[e];
        }
    }
    __syncthreads();   // B1: scores, lt, rl ready

    // ---- postprocess + softmax: row r by 32 lanes (tid>>5), base-2 domain
    {
        const int r = tid >> 5, sj = tid & 31;
        const int i = i0 + r;
        const int* mrow = mask + ((size_t)b*T_SEQ + i)*T_SEQ;
        float* prow = ps + r*WPD;
        float vals[20];
        float m = -INFINITY;
        #pragma unroll
        for (int mm = 0; mm < 5; ++mm) {
            const int j0 = 4*sj + 128*mm;
            float4 pv = make_float4(0.f,0.f,0.f,0.f);
            int4 mv = make_int4(0,0,0,0);
            if (j0 < wlen) {
                pv = *reinterpret_cast<const float4*>(prow + j0);
                mv = *reinterpret_cast<const int4*>(mrow + jlo + j0);  // aligned, in-row
            }
            const float pe[4] = {pv.x, pv.y, pv.z, pv.w};
            const int me[4] = {mv.x, mv.y, mv.z, mv.w};
            #pragma unroll
            for (int e = 0; e < 4; ++e) {
                const int j = j0 + e;
                float val = -INFINITY;
                if (j0 < wlen && j < wlen) {
                    const int dd = jlo + j - i;
                    const int ad = dd < 0 ? -dd : dd;
                    if (ad <= BAND && me[e] != 0) {
                        val = pe[e] - lt[ad];
                        if ((unsigned)(dd + 4) <= 8u) val += rl[r*9 + dd + 4];
                    }
                }
                vals[mm*4 + e] = val;
                m = fmaxf(m, val);
            }
        }
        #pragma unroll
        for (int off = 16; off > 0; off >>= 1) m = fmaxf(m, __shfl_xor(m, off, 64));
        if (m == -INFINITY) m = 0.f;
        float ssum = 0.f;
        #pragma unroll
        for (int u = 0; u < 20; ++u) { vals[u] = exp2f(vals[u] - m); ssum += vals[u]; }
        #pragma unroll
        for (int off = 16; off > 0; off >>= 1) ssum += __shfl_xor(ssum, off, 64);
        const float inv = ssum > 0.f ? 1.f/ssum : 0.f;
        short* pbrow = (short*)prow;
        #pragma unroll
        for (int mm = 0; mm < 5; ++mm) {
            const int j0 = 4*sj + 128*mm;
            if (j0 < WSLOT) {
                bf16x4 w;
                #pragma unroll
                for (int e = 0; e < 4; ++e) w[e] = f2bf_bits(vals[mm*4+e]*inv);
                *reinterpret_cast<bf16x4*>(pbrow + j0) = w;
            }
        }
    }
    __syncthreads();   // B2: bf16 probs ready; rl dead -> pd pool reusable

    // ---- Pd fill (diagonal gather for rel_v MFMA)
    for (int idx = tid; idx < IT*PDS; idx += 1024) {
        const int r = idx / PDS, kk = idx % PDS;
        short v = 0;
        if (kk < 9) {
            const int jg = i0 + r + kk - 4;
            if (jg >= 0 && jg < T_SEQ)
                v = ((const short*)ps)[r*PRS + (jg - jlo)];
        }
        pd_s[idx] = v;
    }

    // ---- PV: 12 output tiles (2 row-tiles x 6 n-tiles) over waves 0..11
    f32x4 o = {0.f,0.f,0.f,0.f};
    const int pri = wave & 1, pnt = wave >> 1;
    if (wave < 12) {
        const short* pbh = (const short*)ps;
        const short* vbase = vtb + qk_base + (size_t)(pnt*16 + lr)*T_SEQ;
        for (int kc = 0; kc < NJT/2; ++kc) {
            const bf16x8 pa = *reinterpret_cast<const bf16x8*>(
                pbh + (pri*16 + lr)*PRS + kc*32 + q4*8);
            int tc = jlo + kc*32 + q4*8;
            if (tc > T_SEQ-8) tc = T_SEQ-8;
            const bf16x8 vb = *reinterpret_cast<const bf16x8*>(vbase + tc);
            o = MFMA16(pa, vb, o, 0, 0, 0);
        }
    }
    __syncthreads();   // B3: pd ready; prob reads done -> ps reusable as out_s

    short* out_s = (short*)ps;          // [32 t][OSTRT] bf16, this head's 96 cols
    if (wave < 12) {
        // rel_v contribution: one MFMA, then stash tile in LDS
        const bf16x8 pda = *reinterpret_cast<const bf16x8*>(pd_s + (pri*16 + lr)*PDS + q4*8);
        const bf16x8 rv  = *reinterpret_cast<const bf16x8*>(rvt + (pnt*16 + lr)*32 + q4*8);
        o = MFMA16(pda, rv, o, 0, 0, 0);
        #pragma unroll
        for (int e = 0; e < 4; ++e)
            out_s[(pri*16 + q4*4 + e)*OSTRT + pnt*16 + lr] = f2bf_bits(o[e]);
    }
    __syncthreads();   // B4: out_s ready

    // ---- fused output-projection tail: 24 jobs (12 dt x 2 rt) over 16 waves
    const short* WoT = (const short*)(ws + OFF_WT(3));
    #pragma unroll
    for (int u = 0; u < 2; ++u) {
        const int j = wave + 16*u;
        if (j < 24) {
            const int dt = j % 12, rt = j / 12;
            f32x4 a = {0.f,0.f,0.f,0.f};
            #pragma unroll
            for (int kc = 0; kc < 3; ++kc) {
                const int ko = kc*32 + q4*8;
                const bf16x8 af = *reinterpret_cast<const bf16x8*>(
                    WoT + (size_t)(dt*16 + lr)*C_DIM + head*K_DIM + ko);
                const bf16x8 bf = *reinterpret_cast<const bf16x8*>(
                    out_s + (rt*16 + lr)*OSTRT + ko);
                a = MFMA16(af, bf, a, 0, 0, 0);
            }
            #pragma unroll
            for (int e = 0; e < 4; ++e) {
                const int d = dt*16 + q4*4 + e;
                atomicAdd(y + ((size_t)b*C_DIM + d)*T_SEQ + i0 + rt*16 + lr, a[e]);
            }
        }
    }
}

// ---------------------------------------------------------------------------
extern "C" void kernel_launch(void* const* d_in, const int* in_sizes, int n_in,
                              void* d_out, int out_size, void* d_ws, size_t ws_size,
                              hipStream_t stream)
{
    const float* x    = (const float*)d_in[0];
    const float* c    = (const float*)d_in[1];
    const float* Wq   = (const float*)d_in[2];
    const float* bq   = (const float*)d_in[3];
    const float* Wk   = (const float*)d_in[4];
    const float* bk   = (const float*)d_in[5];
    const float* Wv   = (const float*)d_in[6];
    const float* bv   = (const float*)d_in[7];
    const float* Wo   = (const float*)d_in[8];
    const float* bo   = (const float*)d_in[9];
    const float* relk = (const float*)d_in[10];
    const float* relv = (const float*)d_in[11];
    const int*   mask = (const int*)d_in[12];
    float*       y    = (float*)d_out;
    char*        ws   = (char*)d_ws;

    hipLaunchKernelGGL(prep_kernel, dim3(529), dim3(256), 0, stream,
                       Wq, Wk, Wv, Wo, bq, relk, relv, bo, y, ws);
    hipLaunchKernelGGL(proj_kernel, dim3(B_DIM*(T_SEQ/32)*3), dim3(256), 0, stream,
                       x, c, bk, bv, ws);
    hipLaunchKernelGGL(attn_kernel, dim3(B_DIM*H_DIM*(T_SEQ/IT)), dim3(1024), 0, stream,
                       mask, y, ws);
}

// Round 10
// 167.270 us; speedup vs baseline: 2.1669x; 1.0068x over previous
//
#include <hip/hip_runtime.h>
#include <hip/hip_bf16.h>

#define B_DIM 4
#define C_DIM 192
#define T_SEQ 2048
#define H_DIM 2
#define K_DIM 96
#define BAND 256
#define IT 16            // q rows per attn block (both heads per block)
#define NJT 34           // j-tiles of 16 in window
#define WSLOT 544        // padded window slots
#define WPD 556          // score row stride in dwords (16B aligned)
#define PRS (2*WPD)      // prob row stride in shorts (bf16 overlay of ps)
#define XSTR 200         // proj LDS row stride in shorts (breaks 16-way conflict)
#define PDS 40           // pd row stride in shorts
#define OSTR 200         // out_s row stride in shorts (400B, 2-way banks)

typedef __attribute__((ext_vector_type(8))) short bf16x8;
typedef __attribute__((ext_vector_type(4))) short bf16x4;
typedef __attribute__((ext_vector_type(4))) float f32x4;
#define MFMA16 __builtin_amdgcn_mfma_f32_16x16x32_bf16

__device__ __forceinline__ short f2bf_bits(float f) {
    union { __hip_bfloat16 h; short s; } u; u.h = __float2bfloat16(f); return u.s;
}

// ---- workspace layout (bytes) ----
// WqT|WkT|WvT|WoT bf16 [192][192] (WqT prescaled by qscale*log2e); bqs fp32[192];
// relkbf bf16[16][96] (rows 9..15 zero); rvt bf16[96][32] (relv^T, cols 9..31 zero);
// qbf,kbf bf16 [bh][t][96]; vtb bf16 [bh][96][t]
#define OFF_WT(m)  ((size_t)(m)*73728)
#define OFF_BQS    ((size_t)294912)
#define OFF_RELKBF ((size_t)295680)
#define OFF_RVT    ((size_t)298752)
#define OFF_QBF    ((size_t)304896)
#define OFF_KBF    (OFF_QBF + 3145728)
#define OFF_VTB    (OFF_KBF + 3145728)

// ---------------------------------------------------------------------------
// Prep: [0,144) LDS-tiled weight transpose; 144: scaled bias + tables.
// NOTE: qscale includes log2(e) -> scores in log2 domain; softmax uses exp2.
// ---------------------------------------------------------------------------
__global__ __launch_bounds__(256)
void prep_kernel(const float* __restrict__ Wq, const float* __restrict__ Wk,
                 const float* __restrict__ Wv, const float* __restrict__ Wo,
                 const float* __restrict__ bq, const float* __restrict__ relk,
                 const float* __restrict__ relv, char* __restrict__ ws)
{
    const float qscale = 0.14724445972f;   // (1/sqrt(96)) * log2(e)
    const int bidx = blockIdx.x;
    const int tid  = threadIdx.x;

    if (bidx < 144) {                       // ---- 32x32 tile transpose via LDS
        __shared__ float tile[32][33];
        const int mi = bidx / 36, tl = bidx % 36;
        const int R0 = (tl / 6) * 32, C0 = (tl % 6) * 32;   // R0: c-rows, C0: d-cols
        const float* src = (mi == 0) ? Wq : (mi == 1) ? Wk : (mi == 2) ? Wv : Wo;
        const int r = tid >> 5, cc = tid & 31;
        #pragma unroll
        for (int i = 0; i < 4; ++i) {
            const int rr = r + 8*i;
            tile[rr][cc] = src[(R0 + rr)*C_DIM + C0 + cc];   // coalesced 128B
        }
        __syncthreads();
        short* dst = (short*)(ws + OFF_WT(mi));
        #pragma unroll
        for (int i = 0; i < 4; ++i) {
            const int rr = r + 8*i;                 // d-row within tile
            float v = tile[cc][rr];                 // conflict-free (stride 33)
            if (mi == 0) v *= qscale;
            dst[(C0 + rr)*C_DIM + R0 + cc] = f2bf_bits(v);   // coalesced 64B
        }
        return;
    }
    // ---- tables
    if (tid < C_DIM)
        ((float*)(ws + OFF_BQS))[tid] = bq[tid]*qscale;
    short* rkb = (short*)(ws + OFF_RELKBF);
    for (int idx = tid; idx < 16*K_DIM; idx += 256) {
        const int row = idx / K_DIM;
        rkb[idx] = (row < 9) ? f2bf_bits(relk[idx]) : (short)0;
    }
    short* rvt = (short*)(ws + OFF_RVT);
    for (int idx = tid; idx < K_DIM*32; idx += 256) {
        const int col = idx >> 5, dd = idx & 31;
        rvt[idx] = (dd < 9) ? f2bf_bits(relv[dd*K_DIM + col]) : (short)0;
    }
}

// ---------------------------------------------------------------------------
// Kernel 1: q/k/v projection, one matrix per block, T=32 rows per block
// (round-5 structure, unchanged). Grid 768, 256 thr, 4 waves x 3 dt x 2 rt.
// ---------------------------------------------------------------------------
__global__ __launch_bounds__(256)
void proj_kernel(const float* __restrict__ x, const float* __restrict__ cin,
                 const float* __restrict__ bk, const float* __restrict__ bv,
                 char* __restrict__ ws)
{
    __shared__ short sb[32*XSTR];   // [32 t][XSTR c] bf16 = 12.8 KB
    const int hw = blockIdx.x;
    const int L  = (hw & 7)*96 + (hw >> 3);    // 768-block XCD-chunked swizzle
    const int which = L % 3;                   // 0=q, 1=k, 2=v
    const int rest  = L / 3;                   // 0..255
    const int b  = rest >> 6;
    const int t0 = (rest & 63) * 32;
    const int tid = threadIdx.x;
    const int wave = tid >> 6, lane = tid & 63;
    const int q4 = lane >> 4, lr = lane & 15;

    const float* src = (which == 0) ? x : cin;
    for (int l = tid; l < 1536; l += 256) {    // 192 c-rows x 8 float4 chunks
        const int cr = l >> 3, u = l & 7;
        const float4 v4 = *reinterpret_cast<const float4*>(
            src + (size_t)(b*C_DIM + cr)*T_SEQ + t0 + 4*u);
        sb[(4*u+0)*XSTR + cr] = f2bf_bits(v4.x);
        sb[(4*u+1)*XSTR + cr] = f2bf_bits(v4.y);
        sb[(4*u+2)*XSTR + cr] = f2bf_bits(v4.z);
        sb[(4*u+3)*XSTR + cr] = f2bf_bits(v4.w);
    }
    __syncthreads();

    const short* WT = (const short*)(ws + OFF_WT(which));
    f32x4 a[3][2];
    #pragma unroll
    for (int j = 0; j < 3; ++j) {
        a[j][0] = (f32x4){0.f,0.f,0.f,0.f};
        a[j][1] = (f32x4){0.f,0.f,0.f,0.f};
    }
    for (int kc = 0; kc < 6; ++kc) {
        const int ko = kc*32 + q4*8;
        const bf16x8 sf0 = *reinterpret_cast<const bf16x8*>(sb + lr*XSTR + ko);
        const bf16x8 sf1 = *reinterpret_cast<const bf16x8*>(sb + (16 + lr)*XSTR + ko);
        #pragma unroll
        for (int j = 0; j < 3; ++j) {
            const bf16x8 wf = *reinterpret_cast<const bf16x8*>(
                WT + ((3*wave + j)*16 + lr)*C_DIM + ko);
            if (which == 2) {                      // v: m=d, n=t
                a[j][0] = MFMA16(wf, sf0, a[j][0], 0, 0, 0);
                a[j][1] = MFMA16(wf, sf1, a[j][1], 0, 0, 0);
            } else {                               // q,k: m=t, n=d
                a[j][0] = MFMA16(sf0, wf, a[j][0], 0, 0, 0);
                a[j][1] = MFMA16(sf1, wf, a[j][1], 0, 0, 0);
            }
        }
    }

    const float* bqs = (const float*)(ws + OFF_BQS);
    #pragma unroll
    for (int j = 0; j < 3; ++j) {
        const int dt = 3*wave + j;
        if (which <= 1) {    // q,k: col=d=dt*16+lr, row=t
            const int d = dt*16 + lr, h = d/K_DIM, kk = d%K_DIM;
            const int bh = b*H_DIM + h;
            const float bias = (which == 0) ? bqs[d] : bk[d];
            short* dst = (short*)(ws + (which == 0 ? OFF_QBF : OFF_KBF));
            #pragma unroll
            for (int rt = 0; rt < 2; ++rt)
                #pragma unroll
                for (int e = 0; e < 4; ++e) {
                    const int t = t0 + rt*16 + q4*4 + e;
                    dst[((size_t)bh*T_SEQ + t)*K_DIM + kk] = f2bf_bits(a[j][rt][e] + bias);
                }
        } else {             // v: col=t, row=d=dt*16+q4*4+e
            short* vtb = (short*)(ws + OFF_VTB);
            #pragma unroll
            for (int rt = 0; rt < 2; ++rt)
                #pragma unroll
                for (int e = 0; e < 4; ++e) {
                    const int d = dt*16 + q4*4 + e, h = d/K_DIM, kk = d%K_DIM;
                    const int bh = b*H_DIM + h;
                    vtb[((size_t)bh*K_DIM + kk)*T_SEQ + t0 + rt*16 + lr] =
                        f2bf_bits(a[j][rt][e] + bv[d]);
                }
        }
    }
}

// ---------------------------------------------------------------------------
// Kernel 2: banded attention, BOTH heads per block, IT=16 rows. 1024 threads
// (16 waves: waves 0-7 head 0, 8-15 head 1 for scores), ~75 KB LDS ->
// 2 blocks/CU = 32 waves/CU. Epilogue owns the full 192-wide out tile ->
// Wo projection with PLAIN stores (no atomics, no y-init).
// ---------------------------------------------------------------------------
__global__ __launch_bounds__(1024, 8)
void attn_kernel(const int* __restrict__ mask, const float* __restrict__ bo,
                 float* __restrict__ y, char* __restrict__ ws)
{
    __shared__ __align__(16) float ps[2*IT*WPD]; // 71168 B scores->probs->out_s
    __shared__ float lt[257];                    // log2(1+d) table
    __shared__ __align__(16) char upool[2560];   // rl(1152) | pd(2560)
    float* rl   = (float*)upool;                 // [2][16][9]
    short* pd_s = (short*)upool;                 // [2][16][PDS] (after rl dead)

    const short* qbf = (const short*)(ws + OFF_QBF);
    const short* kbf = (const short*)(ws + OFF_KBF);
    const short* vtb = (const short*)(ws + OFF_VTB);
    const short* rkb = (const short*)(ws + OFF_RELKBF);
    const short* rvt = (const short*)(ws + OFF_RVT);

    const int L    = ((blockIdx.x & 7) << 6) + (blockIdx.x >> 3);  // 512 blocks
    const int b    = L >> 7;
    const int i0   = (L & 127) * IT;
    const int tid  = threadIdx.x;
    const int wave = tid >> 6, lane = tid & 63;
    const int q4 = lane >> 4, lr = lane & 15;
    const int hh = wave >> 3, wg = wave & 7;    // score-phase head / job group

    const int jlo  = max(0, i0 - BAND);
    const int jhi  = min(T_SEQ - 1, i0 + IT - 1 + BAND);
    const int wlen = jhi - jlo + 1;             // <= 528
    const size_t qk_base = (size_t)(b*H_DIM + hh) * T_SEQ * K_DIM;

    for (int idx = tid; idx < 257; idx += 1024) lt[idx] = log2f((float)(1 + idx));

    // ---- Q A-frags (own head's 16 rows)
    bf16x8 qa[3];
    {
        const short* qrow = qbf + qk_base + (size_t)(i0 + lr)*K_DIM + q4*8;
        #pragma unroll
        for (int kc = 0; kc < 3; ++kc)
            qa[kc] = *reinterpret_cast<const bf16x8*>(qrow + kc*32);
    }

    // ---- scores: 8 waves per head interleave the 34 j-tiles
    float* psh = ps + hh*(IT*WPD);
    for (int jt = wg; jt < NJT; jt += 8) {
        int jr = jlo + jt*16 + lr;
        if (jr > T_SEQ-1) jr = T_SEQ-1;
        const short* krow = kbf + qk_base + (size_t)jr*K_DIM + q4*8;
        f32x4 s = {0.f,0.f,0.f,0.f};
        #pragma unroll
        for (int kc = 0; kc < 3; ++kc)
            s = MFMA16(qa[kc], *reinterpret_cast<const bf16x8*>(krow + kc*32), s, 0, 0, 0);
        float* pr = psh + (q4*4)*WPD + jt*16 + lr;
        pr[0*WPD] = s[0]; pr[1*WPD] = s[1]; pr[2*WPD] = s[2]; pr[3*WPD] = s[3];
    }
    if (wg == 7) {                    // rl[hh][r][dd] = q_r . relk_dd (log2 dom)
        const short* krow = rkb + lr*K_DIM + q4*8;
        f32x4 rs = {0.f,0.f,0.f,0.f};
        #pragma unroll
        for (int kc = 0; kc < 3; ++kc)
            rs = MFMA16(qa[kc], *reinterpret_cast<const bf16x8*>(krow + kc*32), rs, 0, 0, 0);
        if (lr < 9) {
            #pragma unroll
            for (int e = 0; e < 4; ++e)
                rl[hh*144 + (q4*4 + e)*9 + lr] = rs[e];
        }
    }
    __syncthreads();   // B1: scores, lt, rl ready

    // ---- postprocess + softmax: 32 rows (2 heads x 16) by 32 lanes each
    {
        const int rg = tid >> 5, sj = tid & 31;
        const int sh = rg >> 4, r = rg & 15;
        const int i = i0 + r;
        const int* mrow = mask + ((size_t)b*T_SEQ + i)*T_SEQ;
        float* prow = ps + sh*(IT*WPD) + r*WPD;
        float vals[20];
        float m = -INFINITY;
        #pragma unroll
        for (int mm = 0; mm < 5; ++mm) {
            const int j0 = 4*sj + 128*mm;
            float4 pv = make_float4(0.f,0.f,0.f,0.f);
            int4 mv = make_int4(0,0,0,0);
            if (j0 < wlen) {
                pv = *reinterpret_cast<const float4*>(prow + j0);
                mv = *reinterpret_cast<const int4*>(mrow + jlo + j0);  // aligned
            }
            const float pe[4] = {pv.x, pv.y, pv.z, pv.w};
            const int me[4] = {mv.x, mv.y, mv.z, mv.w};
            #pragma unroll
            for (int e = 0; e < 4; ++e) {
                const int j = j0 + e;
                float val = -INFINITY;
                if (j0 < wlen && j < wlen) {
                    const int dd = jlo + j - i;
                    const int ad = dd < 0 ? -dd : dd;
                    if (ad <= BAND && me[e] != 0) {
                        val = pe[e] - lt[ad];
                        if ((unsigned)(dd + 4) <= 8u) val += rl[sh*144 + r*9 + dd + 4];
                    }
                }
                vals[mm*4 + e] = val;
                m = fmaxf(m, val);
            }
        }
        #pragma unroll
        for (int off = 16; off > 0; off >>= 1) m = fmaxf(m, __shfl_xor(m, off, 64));
        if (m == -INFINITY) m = 0.f;
        float ssum = 0.f;
        #pragma unroll
        for (int u = 0; u < 20; ++u) { vals[u] = exp2f(vals[u] - m); ssum += vals[u]; }
        #pragma unroll
        for (int off = 16; off > 0; off >>= 1) ssum += __shfl_xor(ssum, off, 64);
        const float inv = ssum > 0.f ? 1.f/ssum : 0.f;
        short* pbrow = (short*)prow;
        #pragma unroll
        for (int mm = 0; mm < 5; ++mm) {
            const int j0 = 4*sj + 128*mm;
            if (j0 < WSLOT) {
                bf16x4 w;
                #pragma unroll
                for (int e = 0; e < 4; ++e) w[e] = f2bf_bits(vals[mm*4+e]*inv);
                *reinterpret_cast<bf16x4*>(pbrow + j0) = w;
            }
        }
    }
    __syncthreads();   // B2: bf16 probs ready; rl dead -> pd pool reusable

    // ---- Pd fill (diagonal gather for rel_v MFMA), both heads
    for (int idx = tid; idx < 2*IT*PDS; idx += 1024) {
        const int ph = idx / (IT*PDS), rem2 = idx % (IT*PDS);
        const int r = rem2 / PDS, kk = rem2 % PDS;
        short v = 0;
        if (kk < 9) {
            const int jg = i0 + r + kk - 4;
            if (jg >= 0 && jg < T_SEQ)
                v = ((const short*)ps)[ph*(IT*PRS) + r*PRS + (jg - jlo)];
        }
        pd_s[idx] = v;
    }

    // ---- PV: 12 jobs (2 heads x 6 n-tiles) over waves 0..11
    f32x4 o = {0.f,0.f,0.f,0.f};
    const int phh = wave & 1, pnt = wave >> 1;
    if (wave < 12) {
        const size_t pv_base = (size_t)(b*H_DIM + phh) * T_SEQ * K_DIM;
        const short* pbh = (const short*)ps + phh*(IT*PRS);
        const short* vbase = vtb + pv_base + (size_t)(pnt*16 + lr)*T_SEQ;
        for (int kc = 0; kc < NJT/2; ++kc) {
            const bf16x8 pa = *reinterpret_cast<const bf16x8*>(
                pbh + lr*PRS + kc*32 + q4*8);
            int tc = jlo + kc*32 + q4*8;
            if (tc > T_SEQ-8) tc = T_SEQ-8;
            const bf16x8 vb = *reinterpret_cast<const bf16x8*>(vbase + tc);
            o = MFMA16(pa, vb, o, 0, 0, 0);
        }
    }
    __syncthreads();   // B3: pd ready; prob reads done -> ps reusable as out_s

    short* out_s = (short*)ps;          // [16 t][OSTR] bf16, full 192 cols
    if (wave < 12) {
        // rel_v contribution: one MFMA, then stash tile in LDS
        const bf16x8 pda = *reinterpret_cast<const bf16x8*>(
            pd_s + phh*(IT*PDS) + lr*PDS + q4*8);
        const bf16x8 rv  = *reinterpret_cast<const bf16x8*>(rvt + (pnt*16 + lr)*32 + q4*8);
        o = MFMA16(pda, rv, o, 0, 0, 0);
        const int col = phh*K_DIM + pnt*16 + lr;
        #pragma unroll
        for (int e = 0; e < 4; ++e)
            out_s[(q4*4 + e)*OSTR + col] = f2bf_bits(o[e]);
    }
    __syncthreads();   // B4: out_s ready

    // ---- output projection: 12 d-tiles over waves 0..11, plain y stores
    const short* WoT = (const short*)(ws + OFF_WT(3));
    if (wave < 12) {
        const int dt = wave;
        f32x4 a = {0.f,0.f,0.f,0.f};
        #pragma unroll
        for (int kc = 0; kc < 6; ++kc) {
            const int ko = kc*32 + q4*8;
            const bf16x8 af = *reinterpret_cast<const bf16x8*>(
                WoT + (size_t)(dt*16 + lr)*C_DIM + ko);
            const bf16x8 bfr = *reinterpret_cast<const bf16x8*>(
                out_s + lr*OSTR + ko);
            a = MFMA16(af, bfr, a, 0, 0, 0);
        }
        #pragma unroll
        for (int e = 0; e < 4; ++e) {
            const int d = dt*16 + q4*4 + e;
            y[((size_t)b*C_DIM + d)*T_SEQ + i0 + lr] = a[e] + bo[d];
        }
    }
}

// ---------------------------------------------------------------------------
extern "C" void kernel_launch(void* const* d_in, const int* in_sizes, int n_in,
                              void* d_out, int out_size, void* d_ws, size_t ws_size,
                              hipStream_t stream)
{
    const float* x    = (const float*)d_in[0];
    const float* c    = (const float*)d_in[1];
    const float* Wq   = (const float*)d_in[2];
    const float* bq   = (const float*)d_in[3];
    const float* Wk   = (const float*)d_in[4];
    const float* bk   = (const float*)d_in[5];
    const float* Wv   = (const float*)d_in[6];
    const float* bv   = (const float*)d_in[7];
    const float* Wo   = (const float*)d_in[8];
    const float* bo   = (const float*)d_in[9];
    const float* relk = (const float*)d_in[10];
    const float* relv = (const float*)d_in[11];
    const int*   mask = (const int*)d_in[12];
    float*       y    = (float*)d_out;
    char*        ws   = (char*)d_ws;

    hipLaunchKernelGGL(prep_kernel, dim3(145), dim3(256), 0, stream,
                       Wq, Wk, Wv, Wo, bq, relk, relv, ws);
    hipLaunchKernelGGL(proj_kernel, dim3(B_DIM*(T_SEQ/32)*3), dim3(256), 0, stream,
                       x, c, bk, bv, ws);
    hipLaunchKernelGGL(attn_kernel, dim3(B_DIM*(T_SEQ/IT)), dim3(1024), 0, stream,
                       mask, bo, y, ws);
}